// Round 22
// baseline (305.675 us; speedup 1.0000x reference)
//
#include <hip/hip_runtime.h>
#include <math.h>

typedef __attribute__((ext_vector_type(8))) short short8;
typedef __attribute__((ext_vector_type(4))) float f32x4;
typedef unsigned short ushort_t;

#define KVIN 15360   // 15069 padded to 960*16 (split-K x16, K%32==0)

__device__ __forceinline__ ushort_t f2bf(float f) {
  unsigned u = __float_as_uint(f);
  return (ushort_t)((u + 0x7fffu + ((u >> 16) & 1u)) >> 16);  // RNE
}
__device__ __forceinline__ float bf2f(ushort_t h) {
  return __uint_as_float(((unsigned)h) << 16);
}

// ---------------- block reduction helpers (256-thread blocks) ----------------
__device__ __forceinline__ float blockReduceSum256(float v, float* red) {
  #pragma unroll
  for (int o = 32; o; o >>= 1) v += __shfl_xor(v, o);
  int wid = threadIdx.x >> 6, lane = threadIdx.x & 63;
  if (lane == 0) red[wid] = v;
  __syncthreads();
  v = red[0] + red[1] + red[2] + red[3];
  __syncthreads();
  return v;
}
__device__ __forceinline__ float blockReduceMax256(float v, float* red) {
  #pragma unroll
  for (int o = 32; o; o >>= 1) v = fmaxf(v, __shfl_xor(v, o));
  int wid = threadIdx.x >> 6, lane = threadIdx.x & 63;
  if (lane == 0) red[wid] = v;
  __syncthreads();
  v = fmaxf(fmaxf(red[0], red[1]), fmaxf(red[2], red[3]));
  __syncthreads();
  return v;
}

// ===== GEMM body (R12-proven inner loop). OUT16: store bf16 partials (halves traffic).
template <bool BF16B, int BIASM, bool CAUSAL, int ZDIV, bool OUT16>
__device__ __forceinline__ void gemm_body(
    void* smem,
    const ushort_t* __restrict__ A, const void* __restrict__ Bv,
    const float* __restrict__ bias, const float* __restrict__ biasB,
    void* __restrict__ Cv,
    int N, int K, int lda, int ldb, int ldc,
    int kChunk, long aZ, long bZ, long cZ,
    int z, int m0, int n0)
{
  if (CAUSAL && n0 > m0 + 127) return;   // block-uniform
  ushort_t (*sA)[4096] = (ushort_t (*)[4096])smem;
  ushort_t (*sB)[4096] = (ushort_t (*)[4096])((char*)smem + 16384);
  const int tid = threadIdx.x;
  const int ks = ZDIV ? (z % ZDIV) : z;
  const int zb = ZDIV ? (z / ZDIV) : z;
  const int kBeg = kChunk ? ks * kChunk : 0;
  const int kEnd = kChunk ? kBeg + kChunk : K;
  A += (size_t)zb * aZ;
  const ushort_t* Bh = (const ushort_t*)Bv;
  const float*    Bf = (const float*)Bv;
  if (BF16B) Bh += (size_t)zb * bZ; else Bf += (size_t)zb * bZ;
  float*    C32 = (float*)Cv + (OUT16 ? 0 : (size_t)z * cZ);
  ushort_t* C16 = (ushort_t*)Cv + (OUT16 ? (size_t)z * cZ : 0);

  const int r0 = ((tid >> 6) << 4) | (tid & 15);
  const int q0 = (tid >> 4) & 3;
  const int r1 = r0 + 64;
  const ushort_t* pA0 = A + (size_t)(m0 + r0) * lda + (q0 << 3);
  const ushort_t* pA1 = A + (size_t)(m0 + r1) * lda + (q0 << 3);
  const int gn0 = n0 + r0, gn1 = n0 + r1;
  const bool bok0 = gn0 < N, bok1 = gn1 < N;
  const ushort_t* pB0h = Bh + (size_t)gn0 * ldb + (q0 << 3);
  const ushort_t* pB1h = Bh + (size_t)gn1 * ldb + (q0 << 3);
  const float*    pB0f = Bf + (size_t)gn0 * ldb + (q0 << 3);
  const float*    pB1f = Bf + (size_t)gn1 * ldb + (q0 << 3);

  const int lane = tid & 63;
  const int wrb = (tid >> 7) & 1;
  const int wcb = (tid >> 6) & 1;
  const int fr = lane & 15, fq = lane >> 4;

  f32x4 acc[4][4] = {};
  const short8 z8 = {0, 0, 0, 0, 0, 0, 0, 0};
  const float4 z4 = make_float4(0.f, 0.f, 0.f, 0.f);
  short8 ra0, ra1, rb0, rb1; float4 rf0, rf1, rf2, rf3;

#define LOADR(KK) { ra0 = *(const short8*)(pA0 + (KK)); ra1 = *(const short8*)(pA1 + (KK)); \
  if (BF16B) { rb0 = bok0 ? *(const short8*)(pB0h + (KK)) : z8;                             \
               rb1 = bok1 ? *(const short8*)(pB1h + (KK)) : z8; }                           \
  else { rf0 = bok0 ? *(const float4*)(pB0f + (KK)) : z4;                                   \
         rf1 = bok0 ? *(const float4*)(pB0f + (KK) + 4) : z4;                               \
         rf2 = bok1 ? *(const float4*)(pB1f + (KK)) : z4;                                   \
         rf3 = bok1 ? *(const float4*)(pB1f + (KK) + 4) : z4; } }

#define STAGER(BUF) { *(short8*)&sA[BUF][tid << 3] = ra0;                                   \
  *(short8*)&sA[BUF][(tid + 256) << 3] = ra1;                                               \
  if (BF16B) { *(short8*)&sB[BUF][tid << 3] = rb0;                                          \
               *(short8*)&sB[BUF][(tid + 256) << 3] = rb1; }                                \
  else { short8 s0_, s1_;                                                                   \
    _Pragma("unroll") for (int j = 0; j < 4; ++j) {                                         \
      s0_[j] = (short)f2bf(rf0[j]); s0_[j + 4] = (short)f2bf(rf1[j]);                       \
      s1_[j] = (short)f2bf(rf2[j]); s1_[j + 4] = (short)f2bf(rf3[j]); }                     \
    *(short8*)&sB[BUF][tid << 3] = s0_; *(short8*)&sB[BUF][(tid + 256) << 3] = s1_; } }

#define COMPUTE(BUF) { short8 fa[4], fb[4];                                                 \
  _Pragma("unroll") for (int f = 0; f < 4; ++f)                                             \
    fa[f] = *(const short8*)&sA[BUF][((((wrb << 2) + f) << 9) | (lane << 3))];              \
  _Pragma("unroll") for (int g = 0; g < 4; ++g)                                             \
    fb[g] = *(const short8*)&sB[BUF][((((wcb << 2) + g) << 9) | (lane << 3))];              \
  _Pragma("unroll") for (int f = 0; f < 4; ++f)                                             \
    _Pragma("unroll") for (int g = 0; g < 4; ++g)                                           \
      acc[f][g] = __builtin_amdgcn_mfma_f32_16x16x32_bf16(fa[f], fb[g], acc[f][g], 0, 0, 0); }

  LOADR(kBeg);
  const int nt = (kEnd - kBeg) >> 5;
  for (int t = 0; t < nt; ++t) {
    const int cur = t & 1;
    STAGER(cur);                                   // compiler waits vmcnt for R only
    if (t + 1 < nt) LOADR(kBeg + ((t + 1) << 5));  // in flight across the barrier
    asm volatile("s_waitcnt lgkmcnt(0)" ::: "memory");
    __builtin_amdgcn_s_barrier();                  // raw barrier: no vmcnt drain
    __builtin_amdgcn_sched_barrier(0);
    COMPUTE(cur);
    asm volatile("" ::: "memory");
  }

#undef LOADR
#undef STAGER
#undef COMPUTE

  #pragma unroll
  for (int f = 0; f < 4; ++f) {
    const int gm = m0 + (wrb << 6) + f * 16 + fq * 4;
    #pragma unroll
    for (int g = 0; g < 4; ++g) {
      const int gn = n0 + (wcb << 6) + g * 16 + fr;
      if (gn < N) {
        #pragma unroll
        for (int i = 0; i < 4; ++i) {
          float v = acc[f][g][i];
          if (BIASM >= 1) v += bias[gn];
          if (BIASM >= 2) v += biasB[gn];
          const size_t o = (size_t)(gm + i) * ldc + gn;
          if (OUT16) C16[o] = f2bf(v);
          else       C32[o] = v;
        }
      }
    }
  }
}

// ---- single-GEMM wrappers ----
// GMODE 0: (nTile,mTile,z); 1: z-fastest; 2: XCD n-swizzle 1-D; 3: XCD swizzle + split-K z=id/480.
template <bool BF16B, int BIASM, bool CAUSAL, int GMODE, int ZDIV, bool OUT16>
__global__ __launch_bounds__(256, 2) void gk(
    const ushort_t* __restrict__ A, const void* __restrict__ Bv,
    const float* __restrict__ bias, const float* __restrict__ biasB,
    void* __restrict__ C,
    int N, int K, int lda, int ldb, int ldc,
    int kChunk, long aZ, long bZ, long cZ)
{
  extern __shared__ char smem[];
  int z, m0, n0;
  if (GMODE == 3) {
    const int id = blockIdx.x;
    z = id / 480;
    const int r = id % 480, u = r & 7, v = r >> 3;
    m0 = (v & 3) * 128;
    n0 = (((v >> 2) << 3) + u) * 128;
    if (n0 >= N) return;
  } else if (GMODE == 2) {
    const int id = blockIdx.x, u = id & 7, v = id >> 3;
    m0 = (v & 3) * 128;
    n0 = (((v >> 2) << 3) + u) * 128;
    z = 0;
    if (n0 >= N) return;
  } else if (GMODE == 1) {
    z = blockIdx.x; m0 = blockIdx.y * 128; n0 = blockIdx.z * 128;
  } else {
    z = blockIdx.z; m0 = blockIdx.y * 128; n0 = blockIdx.x * 128;
  }
  gemm_body<BF16B, BIASM, CAUSAL, ZDIV, OUT16>(smem, A, Bv, bias, biasB, C,
      N, K, lda, ldb, ldc, kChunk, aZ, bZ, cZ, z, m0, n0);
}

// ---- merged: qkv GEMM (384) || hidden GEMM (128), bf16 partials ----
__global__ __launch_bounds__(256, 2) void gk_qkv_hid(
    const ushort_t* __restrict__ xh, const float* __restrict__ Wqkv,
    ushort_t* __restrict__ partQ,
    const ushort_t* __restrict__ audh, const float* __restrict__ Waf,
    ushort_t* __restrict__ partH)
{
  extern __shared__ char smem[];
  const int bid = blockIdx.x;
  if (bid < 384) {
    const int x = bid % 24, y = (bid / 24) & 3, z = bid / 96;
    gemm_body<false, 0, false, 0, true>(smem, xh, Wqkv, nullptr, nullptr, partQ,
        3072, 1024, 1024, 1024, 3072, 256, 0, 0, 1572864, z, y * 128, x * 128);
  } else {
    const int b = bid - 384;
    const int x = b & 7, y = (b >> 3) & 3, z = b >> 5;
    gemm_body<false, 0, false, 0, true>(smem, audh, Waf, nullptr, nullptr, partH,
        1024, 768, 768, 768, 1024, 192, 0, 0, 524288, z, y * 128, x * 128);
  }
}

// ---- merged: scores GEMM (128, causal, fp32 out) || CA-V GEMM (256, bf16) || W_vr cvt lo ----
__global__ __launch_bounds__(256, 2) void gk_scores_cav(
    const ushort_t* __restrict__ qkvh, float* __restrict__ scores,
    const ushort_t* __restrict__ hidh, const float* __restrict__ WvCA,
    ushort_t* __restrict__ partCV,
    const float* __restrict__ Wvr, ushort_t* __restrict__ Wvrh)
{
  extern __shared__ char smem[];
  const int bid = blockIdx.x;
  if (bid < 128) {
    const int x = bid & 3, y = (bid >> 2) & 3, z = bid >> 4;
    gemm_body<true, 0, true, 0, false>(smem, qkvh, qkvh + 1024, nullptr, nullptr, scores,
        512, 1024, 3072, 3072, 512, 128, 0, 0, 262144, z, y * 128, x * 128);
  } else if (bid < 384) {
    const int b = bid - 128;
    const int x = b & 7, y = (b >> 3) & 3, z = b >> 5;
    gemm_body<false, 0, false, 0, true>(smem, hidh, WvCA, nullptr, nullptr, partCV,
        1024, 1024, 1024, 1024, 1024, 128, 0, 0, 524288, z, y * 128, x * 128);
  } else {
    for (int i = (bid - 384) * 256 + threadIdx.x; i < 1928832; i += 1024 * 256) {
      float4 v = ((const float4*)Wvr)[i];
      ((ushort4*)Wvrh)[i] = make_ushort4(f2bf(v.x), f2bf(v.y), f2bf(v.z), f2bf(v.w));
    }
  }
}

// ---- merged: PV GEMM (128, fp32) || CA-O GEMM (256, bf16) || W_vr cvt hi ----
__global__ __launch_bounds__(256, 2) void gk_pv_cao(
    const ushort_t* __restrict__ atth, const ushort_t* __restrict__ vth,
    float* __restrict__ pvpart,
    const ushort_t* __restrict__ cvh, const float* __restrict__ WoCA,
    ushort_t* __restrict__ partCA,
    const float* __restrict__ Wvr, ushort_t* __restrict__ Wvrh)
{
  extern __shared__ char smem[];
  const int bid = blockIdx.x;
  if (bid < 128) {
    const int x = bid & 1, y = (bid >> 1) & 3, z = bid >> 3;
    gemm_body<true, 0, false, 4, false>(smem, atth, vth, nullptr, nullptr, pvpart,
        256, 512, 512, 512, 256, 128, 262144, 131072, 131072, z, y * 128, x * 128);
  } else if (bid < 384) {
    const int b = bid - 128;
    const int x = b & 7, y = (b >> 3) & 3, z = b >> 5;
    gemm_body<false, 0, false, 0, true>(smem, cvh, WoCA, nullptr, nullptr, partCA,
        1024, 1024, 1024, 1024, 1024, 128, 0, 0, 524288, z, y * 128, x * 128);
  } else {
    for (int i = 1928832 + (bid - 384) * 256 + threadIdx.x; i < 3857664; i += 1024 * 256) {
      float4 v = ((const float4*)Wvr)[i];
      ((ushort4*)Wvrh)[i] = make_ushort4(f2bf(v.x), f2bf(v.y), f2bf(v.z), f2bf(v.w));
    }
  }
}

// ---------------- combine (bf16 partials): outh = bf16(sum_z part[z] + bias (+relu)) ----------------
template <bool RELU>
__global__ __launch_bounds__(256) void combine(
    const ushort_t* __restrict__ part, const float* __restrict__ bias,
    ushort_t* __restrict__ outh, int nz, long zstride, int total4, int N4)
{
  const int i = blockIdx.x * 256 + threadIdx.x;
  if (i >= total4) return;
  float4 s = ((const float4*)bias)[i % N4];
  for (int z = 0; z < nz; ++z) {
    ushort4 p = ((const ushort4*)(part + (size_t)z * zstride))[i];
    s.x += bf2f(p.x); s.y += bf2f(p.y); s.z += bf2f(p.z); s.w += bf2f(p.w);
  }
  if (RELU) {
    s.x = fmaxf(s.x, 0.f); s.y = fmaxf(s.y, 0.f);
    s.z = fmaxf(s.z, 0.f); s.w = fmaxf(s.w, 0.f);
  }
  ((ushort4*)outh)[i] = make_ushort4(f2bf(s.x), f2bf(s.y), f2bf(s.z), f2bf(s.w));
}

// final-out combine: out[e] = p0[e] + p1[e] + b_vr[n] + tmpl[n], fp32, e = t*15069 + n
__global__ __launch_bounds__(256) void combine_out(
    const ushort_t* __restrict__ p0, const ushort_t* __restrict__ p1,
    const float* __restrict__ b_vr, const float* __restrict__ tmpl,
    float* __restrict__ out)
{
  const int i = blockIdx.x * 256 + threadIdx.x;
  if (i >= 1928832) return;   // 512*15069/4
  const int e = i << 2;
  int n = e % 15069;
  ushort4 a = ((const ushort4*)p0)[i];
  ushort4 b = ((const ushort4*)p1)[i];
  float r[4] = {bf2f(a.x) + bf2f(b.x), bf2f(a.y) + bf2f(b.y),
                bf2f(a.z) + bf2f(b.z), bf2f(a.w) + bf2f(b.w)};
  #pragma unroll
  for (int j = 0; j < 4; ++j) {
    out[e + j] = r[j] + b_vr[n] + tmpl[n];
    if (++n >= 15069) n = 0;
  }
}

// PV combine (fp32 partials): ctxh[t][h*256+d] = bf16(sum_{ks<4} pvpart[h*4+ks][t][d])
__global__ __launch_bounds__(256) void combine_pv(
    const float* __restrict__ part, ushort_t* __restrict__ ctxh)
{
  const int t = blockIdx.x, tid = threadIdx.x;
  const int h = tid >> 6, dq = tid & 63;
  float4 s = make_float4(0.f, 0.f, 0.f, 0.f);
  #pragma unroll
  for (int ks = 0; ks < 4; ++ks) {
    float4 p = ((const float4*)(part + (size_t)(h * 4 + ks) * 131072 + (size_t)t * 256))[dq];
    s.x += p.x; s.y += p.y; s.z += p.z; s.w += p.w;
  }
  ((ushort4*)ctxh)[t * 256 + h * 64 + dq] =
      make_ushort4(f2bf(s.x), f2bf(s.y), f2bf(s.z), f2bf(s.w));
}

// ---------------- ln_parts (bf16 partials) ----------------
__global__ __launch_bounds__(256) void ln_parts(
    const ushort_t* __restrict__ part, int nz, const float* __restrict__ bias,
    float* __restrict__ x, ushort_t* __restrict__ xh,
    const float* __restrict__ g, const float* __restrict__ b)
{
  const int t = blockIdx.x, tid = threadIdx.x;
  float4 y = ((const float4*)(x + (size_t)t * 1024))[tid];
  float4 s = ((const float4*)bias)[tid];
  for (int z = 0; z < nz; ++z) {
    ushort4 p = ((const ushort4*)(part + (size_t)z * 524288 + (size_t)t * 1024))[tid];
    s.x += bf2f(p.x); s.y += bf2f(p.y); s.z += bf2f(p.z); s.w += bf2f(p.w);
  }
  y.x += s.x; y.y += s.y; y.z += s.z; y.w += s.w;
  __shared__ float red[4];
  float sum = blockReduceSum256(y.x + y.y + y.z + y.w, red);
  const float m = sum * (1.f / 1024.f);
  float dx = y.x - m, dy = y.y - m, dz = y.z - m, dw = y.w - m;
  float q = blockReduceSum256(dx * dx + dy * dy + dz * dz + dw * dw, red);
  const float rs = rsqrtf(q * (1.f / 1024.f) + 1e-5f);
  float4 gg = ((const float4*)g)[tid], bb = ((const float4*)b)[tid];
  float4 o;
  o.x = dx * rs * gg.x + bb.x;
  o.y = dy * rs * gg.y + bb.y;
  o.z = dz * rs * gg.z + bb.z;
  o.w = dw * rs * gg.w + bb.w;
  ((float4*)(x + (size_t)t * 1024))[tid] = o;
  ((ushort4*)xh)[t * 256 + tid] = make_ushort4(f2bf(o.x), f2bf(o.y), f2bf(o.z), f2bf(o.w));
}

// ---- ln_double (bf16 partials): x = LN2(LN1(x + SA(16z) + boSA) + CA(8z) + boCA) ----
__global__ __launch_bounds__(256) void ln_double(
    const ushort_t* __restrict__ partSA, const float* __restrict__ boSA,
    const ushort_t* __restrict__ partCA, const float* __restrict__ boCA,
    float* __restrict__ x, ushort_t* __restrict__ xh,
    const float* __restrict__ g1, const float* __restrict__ be1,
    const float* __restrict__ g2, const float* __restrict__ be2)
{
  const int t = blockIdx.x, tid = threadIdx.x;
  __shared__ float red[4];
  float4 y = ((const float4*)(x + (size_t)t * 1024))[tid];
  float4 s = ((const float4*)boSA)[tid];
  for (int z = 0; z < 16; ++z) {
    ushort4 p = ((const ushort4*)(partSA + (size_t)z * 524288 + (size_t)t * 1024))[tid];
    s.x += bf2f(p.x); s.y += bf2f(p.y); s.z += bf2f(p.z); s.w += bf2f(p.w);
  }
  y.x += s.x; y.y += s.y; y.z += s.z; y.w += s.w;
  float sum = blockReduceSum256(y.x + y.y + y.z + y.w, red);
  float m = sum * (1.f / 1024.f);
  float dx = y.x - m, dy = y.y - m, dz = y.z - m, dw = y.w - m;
  float q = blockReduceSum256(dx * dx + dy * dy + dz * dz + dw * dw, red);
  float rs = rsqrtf(q * (1.f / 1024.f) + 1e-5f);
  float4 gg = ((const float4*)g1)[tid], bb = ((const float4*)be1)[tid];
  y.x = dx * rs * gg.x + bb.x;
  y.y = dy * rs * gg.y + bb.y;
  y.z = dz * rs * gg.z + bb.z;
  y.w = dw * rs * gg.w + bb.w;
  s = ((const float4*)boCA)[tid];
  for (int z = 0; z < 8; ++z) {
    ushort4 p = ((const ushort4*)(partCA + (size_t)z * 524288 + (size_t)t * 1024))[tid];
    s.x += bf2f(p.x); s.y += bf2f(p.y); s.z += bf2f(p.z); s.w += bf2f(p.w);
  }
  y.x += s.x; y.y += s.y; y.z += s.z; y.w += s.w;
  sum = blockReduceSum256(y.x + y.y + y.z + y.w, red);
  m = sum * (1.f / 1024.f);
  dx = y.x - m; dy = y.y - m; dz = y.z - m; dw = y.w - m;
  q = blockReduceSum256(dx * dx + dy * dy + dz * dz + dw * dw, red);
  rs = rsqrtf(q * (1.f / 1024.f) + 1e-5f);
  gg = ((const float4*)g2)[tid]; bb = ((const float4*)be2)[tid];
  float4 o;
  o.x = dx * rs * gg.x + bb.x;
  o.y = dy * rs * gg.y + bb.y;
  o.z = dz * rs * gg.z + bb.z;
  o.w = dw * rs * gg.w + bb.w;
  ((float4*)(x + (size_t)t * 1024))[tid] = o;
  ((ushort4*)xh)[t * 256 + tid] = make_ushort4(f2bf(o.x), f2bf(o.y), f2bf(o.z), f2bf(o.w));
}

// ---------------- merged prep: vin shift + W_vm pad + audio cvt ----------------
__global__ __launch_bounds__(256) void prep_all(
    const float* __restrict__ vertice, const float* __restrict__ tmpl,
    ushort_t* __restrict__ Aph,
    const float* __restrict__ Wvm, ushort_t* __restrict__ Wvmh,
    const float* __restrict__ audio, ushort_t* __restrict__ audh)
{
  const int bid = blockIdx.x;
  if (bid < 7680) {
    const int i = bid * 256 + threadIdx.x;
    const int C4 = KVIN >> 2;
    const int t = i / C4;
    const int c = (i - t * C4) << 2;
    ushort4 o = make_ushort4(0, 0, 0, 0);
    if (t > 0) {
      const float* s = vertice + (size_t)(t - 1) * 15069 + c;
      if (c + 3 < 15069) {
        o = make_ushort4(f2bf(s[0] - tmpl[c]),     f2bf(s[1] - tmpl[c + 1]),
                         f2bf(s[2] - tmpl[c + 2]), f2bf(s[3] - tmpl[c + 3]));
      } else {
        if (c + 0 < 15069) o.x = f2bf(s[0] - tmpl[c]);
        if (c + 1 < 15069) o.y = f2bf(s[1] - tmpl[c + 1]);
        if (c + 2 < 15069) o.z = f2bf(s[2] - tmpl[c + 2]);
        if (c + 3 < 15069) o.w = f2bf(s[3] - tmpl[c + 3]);
      }
    }
    ((ushort4*)Aph)[i] = o;
  } else if (bid < 23040) {
    const int i = (bid - 7680) * 256 + threadIdx.x;
    const int C4 = KVIN >> 2;
    const int r = i / C4;
    const int c = (i - r * C4) << 2;
    const float* s = Wvm + (size_t)r * 15069 + c;
    ushort4 o = make_ushort4(0, 0, 0, 0);
    if (c + 3 < 15069) {
      o = make_ushort4(f2bf(s[0]), f2bf(s[1]), f2bf(s[2]), f2bf(s[3]));
    } else {
      if (c + 0 < 15069) o.x = f2bf(s[0]);
      if (c + 1 < 15069) o.y = f2bf(s[1]);
      if (c + 2 < 15069) o.z = f2bf(s[2]);
      if (c + 3 < 15069) o.w = f2bf(s[3]);
    }
    ((ushort4*)Wvmh)[i] = o;
  } else {
    const int j = (bid - 23040) * 256 + threadIdx.x;
    if (j < 98304) {
      float4 v = ((const float4*)audio)[j];
      ((ushort4*)audh)[j] = make_ushort4(f2bf(v.x), f2bf(v.y), f2bf(v.z), f2bf(v.w));
    }
  }
}

// ---------------- reduce_pe: vin fp32 partials + style + PE -> x (f32 + bf16) ----------------
__global__ __launch_bounds__(256) void reduce_pe(const float* __restrict__ part,
                                                 const float* __restrict__ one_hot,
                                                 const float* __restrict__ W_obj,
                                                 const float* __restrict__ b_vm,
                                                 float* __restrict__ x,
                                                 ushort_t* __restrict__ xh) {
  const int t = blockIdx.x;
  const float PECOEF = -9.210340371976184f / 512.f;  // -ln(10000)/512
  const int p = t % 25;
  for (int d = threadIdx.x; d < 1024; d += 256) {
    float s = b_vm[d];
    #pragma unroll
    for (int j = 0; j < 8; ++j) s += one_hot[j] * W_obj[d * 8 + j];
    #pragma unroll
    for (int z = 0; z < 16; ++z) s += part[(size_t)z * 524288 + (size_t)t * 1024 + d];
    float arg = (float)p * expf((float)(d >> 1) * PECOEF);
    s += (d & 1) ? cosf(arg) : sinf(arg);
    const size_t idx = (size_t)t * 1024 + d;
    x[idx] = s;
    xh[idx] = f2bf(s);
  }
}

// ---------------- merged qkv post (bf16 partials): combine(qkv) + vT + combine(hid) ----------------
__global__ __launch_bounds__(256) void qkvpost_combhid(
    const ushort_t* __restrict__ partQ, const float* __restrict__ bias,
    ushort_t* __restrict__ qkvh, ushort_t* __restrict__ vth,
    const ushort_t* __restrict__ partH, const float* __restrict__ b_af,
    ushort_t* __restrict__ hidh)
{
  const int bid = blockIdx.x;
  __shared__ float tile[32][33];
  if (bid < 1536) {
    const int i = bid * 256 + threadIdx.x;
    float4 s = ((const float4*)bias)[i % 768];
    #pragma unroll
    for (int z = 0; z < 4; ++z) {
      ushort4 p = ((const ushort4*)(partQ + (size_t)z * 1572864))[i];
      s.x += bf2f(p.x); s.y += bf2f(p.y); s.z += bf2f(p.z); s.w += bf2f(p.w);
    }
    ((ushort4*)qkvh)[i] = make_ushort4(f2bf(s.x), f2bf(s.y), f2bf(s.z), f2bf(s.w));
  } else if (bid < 2048) {
    const int b = bid - 1536;
    const int s0 = (b & 15) * 32, d0 = (b >> 4) * 32;
    const int tx = threadIdx.x & 31, ty = threadIdx.x >> 5;
    for (int r = ty; r < 32; r += 8) {
      float v = bias[2048 + d0 + tx];
      #pragma unroll
      for (int z = 0; z < 4; ++z)
        v += bf2f(partQ[(size_t)z * 1572864 + (size_t)(s0 + r) * 3072 + 2048 + d0 + tx]);
      tile[r][tx] = v;
    }
    __syncthreads();
    for (int r = ty; r < 32; r += 8)
      vth[(size_t)(d0 + r) * 512 + s0 + tx] = f2bf(tile[tx][r]);
  } else {
    const int i = (bid - 2048) * 256 + threadIdx.x;   // < 131072
    float4 s = ((const float4*)b_af)[i % 256];
    #pragma unroll
    for (int z = 0; z < 4; ++z) {
      ushort4 p = ((const ushort4*)(partH + (size_t)z * 524288))[i];
      s.x += bf2f(p.x); s.y += bf2f(p.y); s.z += bf2f(p.z); s.w += bf2f(p.w);
    }
    ((ushort4*)hidh)[i] = make_ushort4(f2bf(s.x), f2bf(s.y), f2bf(s.z), f2bf(s.w));
  }
}

// ---------------- merged: softmax (2048, fp32 scores) + combine(cv) (512, bf16 partials) ----------------
__global__ __launch_bounds__(256) void sm_combcv(
    const float* __restrict__ scores, ushort_t* __restrict__ ah,
    const ushort_t* __restrict__ partCV, const float* __restrict__ bqkv_ca,
    ushort_t* __restrict__ cvh)
{
  const int bid = blockIdx.x;
  __shared__ float red[4];
  if (bid < 2048) {
    const int i = bid & 511, h = bid >> 9;
    const float* r0 = scores + (size_t)(2 * h) * 262144 + (size_t)i * 512;
    const float* r1 = r0 + 262144;
    const size_t rb = ((size_t)h * 512 + i) * 512;
    const int tid = threadIdx.x;
    const int len = i + 1;
    const float sl = exp2f(-2.f * (float)(h + 1));
    const int j0 = tid, j1 = tid + 256;
    float v0 = -INFINITY, v1 = -INFINITY;
    if (j0 < len) v0 = (r0[j0] + r1[j0]) * 0.0625f - sl * (float)((i - j0) / 25);
    if (j1 < len) v1 = (r0[j1] + r1[j1]) * 0.0625f - sl * (float)((i - j1) / 25);
    float m = blockReduceMax256(fmaxf(v0, v1), red);
    float e0 = (j0 < len) ? expf(v0 - m) : 0.f;
    float e1 = (j1 < len) ? expf(v1 - m) : 0.f;
    float s = blockReduceSum256(e0 + e1, red);
    float inv = 1.f / s;
    ah[rb + j0] = f2bf(e0 * inv);
    ah[rb + j1] = f2bf(e1 * inv);
  } else {
    const int i = (bid - 2048) * 256 + threadIdx.x;   // < 131072
    float4 s = ((const float4*)(bqkv_ca + 2048))[i % 256];
    #pragma unroll
    for (int z = 0; z < 8; ++z) {
      ushort4 p = ((const ushort4*)(partCV + (size_t)z * 524288))[i];
      s.x += bf2f(p.x); s.y += bf2f(p.y); s.z += bf2f(p.z); s.w += bf2f(p.w);
    }
    ((ushort4*)cvh)[i] = make_ushort4(f2bf(s.x), f2bf(s.y), f2bf(s.z), f2bf(s.w));
  }
}

// ---------------- host-side launch ----------------
extern "C" void kernel_launch(void* const* d_in, const int* in_sizes, int n_in,
                              void* d_out, int out_size, void* d_ws, size_t ws_size,
                              hipStream_t stream) {
  const float* audio   = (const float*)d_in[0];
  const float* vertice = (const float*)d_in[1];
  const float* tmpl    = (const float*)d_in[2];
  const float* one_hot = (const float*)d_in[3];
  const float* W_af    = (const float*)d_in[4];
  const float* b_af    = (const float*)d_in[5];
  const float* W_vm    = (const float*)d_in[6];
  const float* b_vm    = (const float*)d_in[7];
  const float* W_obj   = (const float*)d_in[8];
  const float* Wqkv_sa = (const float*)d_in[9];
  const float* bqkv_sa = (const float*)d_in[10];
  const float* Wo_sa   = (const float*)d_in[11];
  const float* bo_sa   = (const float*)d_in[12];
  const float* Wqkv_ca = (const float*)d_in[13];
  const float* bqkv_ca = (const float*)d_in[14];
  const float* Wo_ca   = (const float*)d_in[15];
  const float* bo_ca   = (const float*)d_in[16];
  const float* W1      = (const float*)d_in[17];
  const float* b1      = (const float*)d_in[18];
  const float* W2      = (const float*)d_in[19];
  const float* b2      = (const float*)d_in[20];
  const float* g1      = (const float*)d_in[21];
  const float* be1     = (const float*)d_in[22];
  const float* g2      = (const float*)d_in[23];
  const float* be2     = (const float*)d_in[24];
  const float* g3      = (const float*)d_in[25];
  const float* be3     = (const float*)d_in[26];
  const float* W_vr    = (const float*)d_in[27];
  const float* b_vr    = (const float*)d_in[28];
  float* out = (float*)d_out;

  // ---- workspace carve (floats), total ~113 MB ----
  float* base = (float*)d_ws;
  float* apF    = base;                  // 512*15360 us  = 3,932,160 fl
  float* wvmF   = apF + 3932160;         // 1024*15360 us = 7,864,320 fl (Wvm, then Wvr after vin)
  float* part   = wvmF + 7864320;        // 16*524288     = 8,388,608 fl
  float* x      = part + 8388608;        // 524,288
  float* xhF    = x + 524288;            // 262,144 (512*1024 us)
  float* audF   = xhF + 262144;          // 196,608 (512*768 us)
  float* hidF   = audF + 196608;         // 262,144
  float* qkvF   = hidF + 262144;         // 786,432 (512*3072 us)
  float* vtF    = qkvF + 786432;         // 262,144 (1024*512 us)
  float* scores = vtF + 262144;          // 2,097,152 (8 x 512x512 fp32 partials)
  float* attF   = scores + 2097152;      // 524,288 (4*512*512 us)
  float* pvpart = attF + 524288;         // 2,097,152 (16 x 512x256 fp32 partials)
  float* ctxF   = pvpart + 2097152;      // 262,144
  float* cvF    = ctxF + 262144;         // 262,144
  float* h1F    = cvF + 262144;          // 524,288 (512*2048 us)

  // bf16 partial sub-regions inside `part` (disjoint lifetimes, element = ushort):
  ushort_t* partQ  = (ushort_t*)part;                   // 4 x 1,572,864 us (steps 4-5)
  ushort_t* partH  = (ushort_t*)(part + 4194304);       // 4 x   524,288 us (steps 4-5)
  ushort_t* partCV = (ushort_t*)part;                   // 8 x   524,288 us (steps 6-7)
  ushort_t* partCA = (ushort_t*)(part + 4194304);       // 8 x   524,288 us (steps 8-11)
  ushort_t* partSA = (ushort_t*)part;                   // 16 x  524,288 us (steps 10-11)
  ushort_t* partF1 = (ushort_t*)part;                   // 8 x 1,048,576 us (steps 12-13)
  ushort_t* partF2 = (ushort_t*)part;                   // 16 x  524,288 us (steps 14-15)
  ushort_t* partO  = (ushort_t*)part;                   // 2 x 7,715,328 us (steps 16-17)

  ushort_t* Aph  = (ushort_t*)apF;
  ushort_t* Wvmh = (ushort_t*)wvmF;
  ushort_t* Wvrh = (ushort_t*)wvmF;      // alias: Wvm dead after vin GEMM
  ushort_t* xh   = (ushort_t*)xhF;
  ushort_t* audh = (ushort_t*)audF;
  ushort_t* hidh = (ushort_t*)hidF;
  ushort_t* qkvh = (ushort_t*)qkvF;
  ushort_t* vth  = (ushort_t*)vtF;
  ushort_t* atth = (ushort_t*)attF;
  ushort_t* ctxh = (ushort_t*)ctxF;
  ushort_t* cvh  = (ushort_t*)cvF;
  ushort_t* h1h  = (ushort_t*)h1F;

  // 1. prep: vin shift + W_vm cvt + audio cvt (merged)
  prep_all<<<23424, 256, 0, stream>>>(vertice, tmpl, Aph, W_vm, Wvmh, audio, audh);

  // 2. vin = Ap @ Wvm^T (split-K x16, z-fastest, fp32 partials)
  gk<true, 0, false, 1, 0, false><<<dim3(16, 4, 8), 256, 32768, stream>>>(
      Aph, Wvmh, nullptr, nullptr, part,
      1024, KVIN, KVIN, KVIN, 1024, 960, 0, 0, 524288);

  // 3. reduce_pe (vin partials -> x, xh)
  reduce_pe<<<512, 256, 0, stream>>>(part, one_hot, W_obj, b_vm, x, xh);

  // 4. qkv GEMM || hidden GEMM (bf16 partials)
  gk_qkv_hid<<<512, 256, 32768, stream>>>(xh, Wqkv_sa, partQ, audh, W_af, partH);

  // 5. qkv combine + vT transpose + hidden combine (merged)
  qkvpost_combhid<<<2560, 256, 0, stream>>>(partQ, bqkv_sa, qkvh, vth,
                                            partH, b_af, hidh);

  // 6. scores GEMM || CA-V GEMM || W_vr cvt lo-half
  gk_scores_cav<<<1408, 256, 32768, stream>>>(qkvh, scores, hidh,
                                              Wqkv_ca + (size_t)2048 * 1024, partCV,
                                              W_vr, Wvrh);

  // 7. softmax + CA-V combine (merged)
  sm_combcv<<<2560, 256, 0, stream>>>(scores, atth, partCV, bqkv_ca, cvh);

  // 8. PV GEMM || CA-O GEMM || W_vr cvt hi-half
  gk_pv_cao<<<1408, 256, 32768, stream>>>(atth, vth, pvpart, cvh, Wo_ca, partCA,
                                          W_vr, Wvrh);

  // 9. PV combine
  combine_pv<<<512, 256, 0, stream>>>(pvpart, ctxh);

  // 10. SA out-proj (bf16 partials, split-K x16 -> 512 blocks, 2/CU)
  gk<false, 0, false, 0, 0, true><<<dim3(8, 4, 16), 256, 32768, stream>>>(
      ctxh, Wo_sa, nullptr, nullptr, partSA,
      1024, 1024, 1024, 1024, 1024, 64, 0, 0, 524288);

  // 11. ln1 + ln2 fused (SA 16 partials lower, CA 8 partials upper)
  ln_double<<<512, 256, 0, stream>>>(partSA, bo_sa, partCA, bo_ca,
                                     x, xh, g1, be1, g2, be2);

  // 12. FF1 (bf16 partials, split-K x8 -> 512 blocks)
  gk<false, 0, false, 0, 0, true><<<dim3(16, 4, 8), 256, 32768, stream>>>(
      xh, W1, nullptr, nullptr, partF1,
      2048, 1024, 1024, 1024, 2048, 128, 0, 0, 1048576);
  // 13. FF1 combine + relu
  combine<true><<<1024, 256, 0, stream>>>(partF1, b1, h1h, 8, 1048576, 262144, 512);
  // 14. FF2 (bf16 partials, split-K x16 -> 512 blocks)
  gk<false, 0, false, 0, 0, true><<<dim3(8, 4, 16), 256, 32768, stream>>>(
      h1h, W2, nullptr, nullptr, partF2,
      1024, 2048, 2048, 2048, 1024, 128, 0, 0, 524288);
  // 15. ln3
  ln_parts<<<512, 256, 0, stream>>>(partF2, 16, b2, x, xh, g3, be3);

  // 16. final projection split-K x2 (960 blocks, 3.75/CU; bf16 partials, XCD swizzle)
  gk<true, 0, false, 3, 2, true><<<dim3(960, 1, 1), 256, 32768, stream>>>(
      xh, Wvrh, nullptr, nullptr, partO,
      15069, 1024, 1024, 1024, 15069, 512, 0, 0, 7715328);

  // 17. final combine: out = p0 + p1 + b_vr + tmpl (fp32)
  combine_out<<<7535, 256, 0, stream>>>(partO, partO + 7715328, b_vr, tmpl, out);
}

// Round 23
// 281.768 us; speedup vs baseline: 1.0848x; 1.0848x over previous
//
#include <hip/hip_runtime.h>
#include <math.h>

typedef __attribute__((ext_vector_type(8))) short short8;
typedef __attribute__((ext_vector_type(4))) float f32x4;
typedef unsigned short ushort_t;

#define KVIN 15360   // 15069 padded to 960*16 (split-K x16, K%32==0)

__device__ __forceinline__ ushort_t f2bf(float f) {
  unsigned u = __float_as_uint(f);
  return (ushort_t)((u + 0x7fffu + ((u >> 16) & 1u)) >> 16);  // RNE
}
__device__ __forceinline__ float bf2f(ushort_t h) {
  return __uint_as_float(((unsigned)h) << 16);
}

// ---------------- block reduction helpers (256-thread blocks) ----------------
__device__ __forceinline__ float blockReduceSum256(float v, float* red) {
  #pragma unroll
  for (int o = 32; o; o >>= 1) v += __shfl_xor(v, o);
  int wid = threadIdx.x >> 6, lane = threadIdx.x & 63;
  if (lane == 0) red[wid] = v;
  __syncthreads();
  v = red[0] + red[1] + red[2] + red[3];
  __syncthreads();
  return v;
}
__device__ __forceinline__ float blockReduceMax256(float v, float* red) {
  #pragma unroll
  for (int o = 32; o; o >>= 1) v = fmaxf(v, __shfl_xor(v, o));
  int wid = threadIdx.x >> 6, lane = threadIdx.x & 63;
  if (lane == 0) red[wid] = v;
  __syncthreads();
  v = fmaxf(fmaxf(red[0], red[1]), fmaxf(red[2], red[3]));
  __syncthreads();
  return v;
}

// ===== GEMM body (R12-proven inner loop). OUT16: store bf16 partials (halves traffic).
template <bool BF16B, int BIASM, bool CAUSAL, int ZDIV, bool OUT16>
__device__ __forceinline__ void gemm_body(
    void* smem,
    const ushort_t* __restrict__ A, const void* __restrict__ Bv,
    const float* __restrict__ bias, const float* __restrict__ biasB,
    void* __restrict__ Cv,
    int N, int K, int lda, int ldb, int ldc,
    int kChunk, long aZ, long bZ, long cZ,
    int z, int m0, int n0)
{
  if (CAUSAL && n0 > m0 + 127) return;   // block-uniform
  ushort_t (*sA)[4096] = (ushort_t (*)[4096])smem;
  ushort_t (*sB)[4096] = (ushort_t (*)[4096])((char*)smem + 16384);
  const int tid = threadIdx.x;
  const int ks = ZDIV ? (z % ZDIV) : z;
  const int zb = ZDIV ? (z / ZDIV) : z;
  const int kBeg = kChunk ? ks * kChunk : 0;
  const int kEnd = kChunk ? kBeg + kChunk : K;
  A += (size_t)zb * aZ;
  const ushort_t* Bh = (const ushort_t*)Bv;
  const float*    Bf = (const float*)Bv;
  if (BF16B) Bh += (size_t)zb * bZ; else Bf += (size_t)zb * bZ;
  float*    C32 = (float*)Cv + (OUT16 ? 0 : (size_t)z * cZ);
  ushort_t* C16 = (ushort_t*)Cv + (OUT16 ? (size_t)z * cZ : 0);

  const int r0 = ((tid >> 6) << 4) | (tid & 15);
  const int q0 = (tid >> 4) & 3;
  const int r1 = r0 + 64;
  const ushort_t* pA0 = A + (size_t)(m0 + r0) * lda + (q0 << 3);
  const ushort_t* pA1 = A + (size_t)(m0 + r1) * lda + (q0 << 3);
  const int gn0 = n0 + r0, gn1 = n0 + r1;
  const bool bok0 = gn0 < N, bok1 = gn1 < N;
  const ushort_t* pB0h = Bh + (size_t)gn0 * ldb + (q0 << 3);
  const ushort_t* pB1h = Bh + (size_t)gn1 * ldb + (q0 << 3);
  const float*    pB0f = Bf + (size_t)gn0 * ldb + (q0 << 3);
  const float*    pB1f = Bf + (size_t)gn1 * ldb + (q0 << 3);

  const int lane = tid & 63;
  const int wrb = (tid >> 7) & 1;
  const int wcb = (tid >> 6) & 1;
  const int fr = lane & 15, fq = lane >> 4;

  f32x4 acc[4][4] = {};
  const short8 z8 = {0, 0, 0, 0, 0, 0, 0, 0};
  const float4 z4 = make_float4(0.f, 0.f, 0.f, 0.f);
  short8 ra0, ra1, rb0, rb1; float4 rf0, rf1, rf2, rf3;

#define LOADR(KK) { ra0 = *(const short8*)(pA0 + (KK)); ra1 = *(const short8*)(pA1 + (KK)); \
  if (BF16B) { rb0 = bok0 ? *(const short8*)(pB0h + (KK)) : z8;                             \
               rb1 = bok1 ? *(const short8*)(pB1h + (KK)) : z8; }                           \
  else { rf0 = bok0 ? *(const float4*)(pB0f + (KK)) : z4;                                   \
         rf1 = bok0 ? *(const float4*)(pB0f + (KK) + 4) : z4;                               \
         rf2 = bok1 ? *(const float4*)(pB1f + (KK)) : z4;                                   \
         rf3 = bok1 ? *(const float4*)(pB1f + (KK) + 4) : z4; } }

#define STAGER(BUF) { *(short8*)&sA[BUF][tid << 3] = ra0;                                   \
  *(short8*)&sA[BUF][(tid + 256) << 3] = ra1;                                               \
  if (BF16B) { *(short8*)&sB[BUF][tid << 3] = rb0;                                          \
               *(short8*)&sB[BUF][(tid + 256) << 3] = rb1; }                                \
  else { short8 s0_, s1_;                                                                   \
    _Pragma("unroll") for (int j = 0; j < 4; ++j) {                                         \
      s0_[j] = (short)f2bf(rf0[j]); s0_[j + 4] = (short)f2bf(rf1[j]);                       \
      s1_[j] = (short)f2bf(rf2[j]); s1_[j + 4] = (short)f2bf(rf3[j]); }                     \
    *(short8*)&sB[BUF][tid << 3] = s0_; *(short8*)&sB[BUF][(tid + 256) << 3] = s1_; } }

#define COMPUTE(BUF) { short8 fa[4], fb[4];                                                 \
  _Pragma("unroll") for (int f = 0; f < 4; ++f)                                             \
    fa[f] = *(const short8*)&sA[BUF][((((wrb << 2) + f) << 9) | (lane << 3))];              \
  _Pragma("unroll") for (int g = 0; g < 4; ++g)                                             \
    fb[g] = *(const short8*)&sB[BUF][((((wcb << 2) + g) << 9) | (lane << 3))];              \
  _Pragma("unroll") for (int f = 0; f < 4; ++f)                                             \
    _Pragma("unroll") for (int g = 0; g < 4; ++g)                                           \
      acc[f][g] = __builtin_amdgcn_mfma_f32_16x16x32_bf16(fa[f], fb[g], acc[f][g], 0, 0, 0); }

  LOADR(kBeg);
  const int nt = (kEnd - kBeg) >> 5;
  for (int t = 0; t < nt; ++t) {
    const int cur = t & 1;
    STAGER(cur);                                   // compiler waits vmcnt for R only
    if (t + 1 < nt) LOADR(kBeg + ((t + 1) << 5));  // in flight across the barrier
    asm volatile("s_waitcnt lgkmcnt(0)" ::: "memory");
    __builtin_amdgcn_s_barrier();                  // raw barrier: no vmcnt drain
    __builtin_amdgcn_sched_barrier(0);
    COMPUTE(cur);
    asm volatile("" ::: "memory");
  }

#undef LOADR
#undef STAGER
#undef COMPUTE

  #pragma unroll
  for (int f = 0; f < 4; ++f) {
    const int gm = m0 + (wrb << 6) + f * 16 + fq * 4;
    #pragma unroll
    for (int g = 0; g < 4; ++g) {
      const int gn = n0 + (wcb << 6) + g * 16 + fr;
      if (gn < N) {
        #pragma unroll
        for (int i = 0; i < 4; ++i) {
          float v = acc[f][g][i];
          if (BIASM >= 1) v += bias[gn];
          if (BIASM >= 2) v += biasB[gn];
          const size_t o = (size_t)(gm + i) * ldc + gn;
          if (OUT16) C16[o] = f2bf(v);
          else       C32[o] = v;
        }
      }
    }
  }
}

// ---- single-GEMM wrappers ----
template <bool BF16B, int BIASM, bool CAUSAL, int GMODE, int ZDIV, bool OUT16>
__global__ __launch_bounds__(256, 2) void gk(
    const ushort_t* __restrict__ A, const void* __restrict__ Bv,
    const float* __restrict__ bias, const float* __restrict__ biasB,
    void* __restrict__ C,
    int N, int K, int lda, int ldb, int ldc,
    int kChunk, long aZ, long bZ, long cZ)
{
  extern __shared__ char smem[];
  int z, m0, n0;
  if (GMODE == 2) {
    const int id = blockIdx.x, u = id & 7, v = id >> 3;
    m0 = (v & 3) * 128;
    n0 = (((v >> 2) << 3) + u) * 128;
    z = 0;
    if (n0 >= N) return;
  } else if (GMODE == 1) {
    z = blockIdx.x; m0 = blockIdx.y * 128; n0 = blockIdx.z * 128;
  } else {
    z = blockIdx.z; m0 = blockIdx.y * 128; n0 = blockIdx.x * 128;
  }
  gemm_body<BF16B, BIASM, CAUSAL, ZDIV, OUT16>(smem, A, Bv, bias, biasB, C,
      N, K, lda, ldb, ldc, kChunk, aZ, bZ, cZ, z, m0, n0);
}

// ---- merged: qkv GEMM (384) || hidden GEMM (128), bf16 partials ----
__global__ __launch_bounds__(256, 2) void gk_qkv_hid(
    const ushort_t* __restrict__ xh, const float* __restrict__ Wqkv,
    ushort_t* __restrict__ partQ,
    const ushort_t* __restrict__ audh, const float* __restrict__ Waf,
    ushort_t* __restrict__ partH)
{
  extern __shared__ char smem[];
  const int bid = blockIdx.x;
  if (bid < 384) {
    const int x = bid % 24, y = (bid / 24) & 3, z = bid / 96;
    gemm_body<false, 0, false, 0, true>(smem, xh, Wqkv, nullptr, nullptr, partQ,
        3072, 1024, 1024, 1024, 3072, 256, 0, 0, 1572864, z, y * 128, x * 128);
  } else {
    const int b = bid - 384;
    const int x = b & 7, y = (b >> 3) & 3, z = b >> 5;
    gemm_body<false, 0, false, 0, true>(smem, audh, Waf, nullptr, nullptr, partH,
        1024, 768, 768, 768, 1024, 192, 0, 0, 524288, z, y * 128, x * 128);
  }
}

// ---- merged: scores GEMM (128, causal, fp32 out) || CA-V GEMM (256, bf16) || W_vr cvt lo ----
__global__ __launch_bounds__(256, 2) void gk_scores_cav(
    const ushort_t* __restrict__ qkvh, float* __restrict__ scores,
    const ushort_t* __restrict__ hidh, const float* __restrict__ WvCA,
    ushort_t* __restrict__ partCV,
    const float* __restrict__ Wvr, ushort_t* __restrict__ Wvrh)
{
  extern __shared__ char smem[];
  const int bid = blockIdx.x;
  if (bid < 128) {
    const int x = bid & 3, y = (bid >> 2) & 3, z = bid >> 4;
    gemm_body<true, 0, true, 0, false>(smem, qkvh, qkvh + 1024, nullptr, nullptr, scores,
        512, 1024, 3072, 3072, 512, 128, 0, 0, 262144, z, y * 128, x * 128);
  } else if (bid < 384) {
    const int b = bid - 128;
    const int x = b & 7, y = (b >> 3) & 3, z = b >> 5;
    gemm_body<false, 0, false, 0, true>(smem, hidh, WvCA, nullptr, nullptr, partCV,
        1024, 1024, 1024, 1024, 1024, 128, 0, 0, 524288, z, y * 128, x * 128);
  } else {
    for (int i = (bid - 384) * 256 + threadIdx.x; i < 1928832; i += 1024 * 256) {
      float4 v = ((const float4*)Wvr)[i];
      ((ushort4*)Wvrh)[i] = make_ushort4(f2bf(v.x), f2bf(v.y), f2bf(v.z), f2bf(v.w));
    }
  }
}

// ---- merged: PV GEMM (128, fp32) || CA-O GEMM (256, bf16) || W_vr cvt hi ----
__global__ __launch_bounds__(256, 2) void gk_pv_cao(
    const ushort_t* __restrict__ atth, const ushort_t* __restrict__ vth,
    float* __restrict__ pvpart,
    const ushort_t* __restrict__ cvh, const float* __restrict__ WoCA,
    ushort_t* __restrict__ partCA,
    const float* __restrict__ Wvr, ushort_t* __restrict__ Wvrh)
{
  extern __shared__ char smem[];
  const int bid = blockIdx.x;
  if (bid < 128) {
    const int x = bid & 1, y = (bid >> 1) & 3, z = bid >> 3;
    gemm_body<true, 0, false, 4, false>(smem, atth, vth, nullptr, nullptr, pvpart,
        256, 512, 512, 512, 256, 128, 262144, 131072, 131072, z, y * 128, x * 128);
  } else if (bid < 384) {
    const int b = bid - 128;
    const int x = b & 7, y = (b >> 3) & 3, z = b >> 5;
    gemm_body<false, 0, false, 0, true>(smem, cvh, WoCA, nullptr, nullptr, partCA,
        1024, 1024, 1024, 1024, 1024, 128, 0, 0, 524288, z, y * 128, x * 128);
  } else {
    for (int i = 1928832 + (bid - 384) * 256 + threadIdx.x; i < 3857664; i += 1024 * 256) {
      float4 v = ((const float4*)Wvr)[i];
      ((ushort4*)Wvrh)[i] = make_ushort4(f2bf(v.x), f2bf(v.y), f2bf(v.z), f2bf(v.w));
    }
  }
}

// ---------------- combine (bf16 partials): outh = bf16(sum_z part[z] + bias (+relu)) ----------------
template <bool RELU>
__global__ __launch_bounds__(256) void combine(
    const ushort_t* __restrict__ part, const float* __restrict__ bias,
    ushort_t* __restrict__ outh, int nz, long zstride, int total4, int N4)
{
  const int i = blockIdx.x * 256 + threadIdx.x;
  if (i >= total4) return;
  float4 s = ((const float4*)bias)[i % N4];
  for (int z = 0; z < nz; ++z) {
    ushort4 p = ((const ushort4*)(part + (size_t)z * zstride))[i];
    s.x += bf2f(p.x); s.y += bf2f(p.y); s.z += bf2f(p.z); s.w += bf2f(p.w);
  }
  if (RELU) {
    s.x = fmaxf(s.x, 0.f); s.y = fmaxf(s.y, 0.f);
    s.z = fmaxf(s.z, 0.f); s.w = fmaxf(s.w, 0.f);
  }
  ((ushort4*)outh)[i] = make_ushort4(f2bf(s.x), f2bf(s.y), f2bf(s.z), f2bf(s.w));
}

// PV combine (fp32 partials): ctxh[t][h*256+d] = bf16(sum_{ks<4} pvpart[h*4+ks][t][d])
__global__ __launch_bounds__(256) void combine_pv(
    const float* __restrict__ part, ushort_t* __restrict__ ctxh)
{
  const int t = blockIdx.x, tid = threadIdx.x;
  const int h = tid >> 6, dq = tid & 63;
  float4 s = make_float4(0.f, 0.f, 0.f, 0.f);
  #pragma unroll
  for (int ks = 0; ks < 4; ++ks) {
    float4 p = ((const float4*)(part + (size_t)(h * 4 + ks) * 131072 + (size_t)t * 256))[dq];
    s.x += p.x; s.y += p.y; s.z += p.z; s.w += p.w;
  }
  ((ushort4*)ctxh)[t * 256 + h * 64 + dq] =
      make_ushort4(f2bf(s.x), f2bf(s.y), f2bf(s.z), f2bf(s.w));
}

// ---------------- ln_parts (bf16 partials) ----------------
__global__ __launch_bounds__(256) void ln_parts(
    const ushort_t* __restrict__ part, int nz, const float* __restrict__ bias,
    float* __restrict__ x, ushort_t* __restrict__ xh,
    const float* __restrict__ g, const float* __restrict__ b)
{
  const int t = blockIdx.x, tid = threadIdx.x;
  float4 y = ((const float4*)(x + (size_t)t * 1024))[tid];
  float4 s = ((const float4*)bias)[tid];
  for (int z = 0; z < nz; ++z) {
    ushort4 p = ((const ushort4*)(part + (size_t)z * 524288 + (size_t)t * 1024))[tid];
    s.x += bf2f(p.x); s.y += bf2f(p.y); s.z += bf2f(p.z); s.w += bf2f(p.w);
  }
  y.x += s.x; y.y += s.y; y.z += s.z; y.w += s.w;
  __shared__ float red[4];
  float sum = blockReduceSum256(y.x + y.y + y.z + y.w, red);
  const float m = sum * (1.f / 1024.f);
  float dx = y.x - m, dy = y.y - m, dz = y.z - m, dw = y.w - m;
  float q = blockReduceSum256(dx * dx + dy * dy + dz * dz + dw * dw, red);
  const float rs = rsqrtf(q * (1.f / 1024.f) + 1e-5f);
  float4 gg = ((const float4*)g)[tid], bb = ((const float4*)b)[tid];
  float4 o;
  o.x = dx * rs * gg.x + bb.x;
  o.y = dy * rs * gg.y + bb.y;
  o.z = dz * rs * gg.z + bb.z;
  o.w = dw * rs * gg.w + bb.w;
  ((float4*)(x + (size_t)t * 1024))[tid] = o;
  ((ushort4*)xh)[t * 256 + tid] = make_ushort4(f2bf(o.x), f2bf(o.y), f2bf(o.z), f2bf(o.w));
}

// ---- ln_double (bf16 partials): x = LN2(LN1(x + SA + boSA) + CA + boCA) ----
__global__ __launch_bounds__(256) void ln_double(
    const ushort_t* __restrict__ partSA, const float* __restrict__ boSA,
    const ushort_t* __restrict__ partCA, const float* __restrict__ boCA,
    float* __restrict__ x, ushort_t* __restrict__ xh,
    const float* __restrict__ g1, const float* __restrict__ be1,
    const float* __restrict__ g2, const float* __restrict__ be2)
{
  const int t = blockIdx.x, tid = threadIdx.x;
  __shared__ float red[4];
  float4 y = ((const float4*)(x + (size_t)t * 1024))[tid];
  float4 s = ((const float4*)boSA)[tid];
  for (int z = 0; z < 8; ++z) {
    ushort4 p = ((const ushort4*)(partSA + (size_t)z * 524288 + (size_t)t * 1024))[tid];
    s.x += bf2f(p.x); s.y += bf2f(p.y); s.z += bf2f(p.z); s.w += bf2f(p.w);
  }
  y.x += s.x; y.y += s.y; y.z += s.z; y.w += s.w;
  float sum = blockReduceSum256(y.x + y.y + y.z + y.w, red);
  float m = sum * (1.f / 1024.f);
  float dx = y.x - m, dy = y.y - m, dz = y.z - m, dw = y.w - m;
  float q = blockReduceSum256(dx * dx + dy * dy + dz * dz + dw * dw, red);
  float rs = rsqrtf(q * (1.f / 1024.f) + 1e-5f);
  float4 gg = ((const float4*)g1)[tid], bb = ((const float4*)be1)[tid];
  y.x = dx * rs * gg.x + bb.x;
  y.y = dy * rs * gg.y + bb.y;
  y.z = dz * rs * gg.z + bb.z;
  y.w = dw * rs * gg.w + bb.w;
  s = ((const float4*)boCA)[tid];
  for (int z = 0; z < 8; ++z) {
    ushort4 p = ((const ushort4*)(partCA + (size_t)z * 524288 + (size_t)t * 1024))[tid];
    s.x += bf2f(p.x); s.y += bf2f(p.y); s.z += bf2f(p.z); s.w += bf2f(p.w);
  }
  y.x += s.x; y.y += s.y; y.z += s.z; y.w += s.w;
  sum = blockReduceSum256(y.x + y.y + y.z + y.w, red);
  m = sum * (1.f / 1024.f);
  dx = y.x - m; dy = y.y - m; dz = y.z - m; dw = y.w - m;
  q = blockReduceSum256(dx * dx + dy * dy + dz * dz + dw * dw, red);
  rs = rsqrtf(q * (1.f / 1024.f) + 1e-5f);
  gg = ((const float4*)g2)[tid]; bb = ((const float4*)be2)[tid];
  float4 o;
  o.x = dx * rs * gg.x + bb.x;
  o.y = dy * rs * gg.y + bb.y;
  o.z = dz * rs * gg.z + bb.z;
  o.w = dw * rs * gg.w + bb.w;
  ((float4*)(x + (size_t)t * 1024))[tid] = o;
  ((ushort4*)xh)[t * 256 + tid] = make_ushort4(f2bf(o.x), f2bf(o.y), f2bf(o.z), f2bf(o.w));
}

// ---------------- merged prep: vin shift + W_vm pad + audio cvt ----------------
__global__ __launch_bounds__(256) void prep_all(
    const float* __restrict__ vertice, const float* __restrict__ tmpl,
    ushort_t* __restrict__ Aph,
    const float* __restrict__ Wvm, ushort_t* __restrict__ Wvmh,
    const float* __restrict__ audio, ushort_t* __restrict__ audh)
{
  const int bid = blockIdx.x;
  if (bid < 7680) {
    const int i = bid * 256 + threadIdx.x;
    const int C4 = KVIN >> 2;
    const int t = i / C4;
    const int c = (i - t * C4) << 2;
    ushort4 o = make_ushort4(0, 0, 0, 0);
    if (t > 0) {
      const float* s = vertice + (size_t)(t - 1) * 15069 + c;
      if (c + 3 < 15069) {
        o = make_ushort4(f2bf(s[0] - tmpl[c]),     f2bf(s[1] - tmpl[c + 1]),
                         f2bf(s[2] - tmpl[c + 2]), f2bf(s[3] - tmpl[c + 3]));
      } else {
        if (c + 0 < 15069) o.x = f2bf(s[0] - tmpl[c]);
        if (c + 1 < 15069) o.y = f2bf(s[1] - tmpl[c + 1]);
        if (c + 2 < 15069) o.z = f2bf(s[2] - tmpl[c + 2]);
        if (c + 3 < 15069) o.w = f2bf(s[3] - tmpl[c + 3]);
      }
    }
    ((ushort4*)Aph)[i] = o;
  } else if (bid < 23040) {
    const int i = (bid - 7680) * 256 + threadIdx.x;
    const int C4 = KVIN >> 2;
    const int r = i / C4;
    const int c = (i - r * C4) << 2;
    const float* s = Wvm + (size_t)r * 15069 + c;
    ushort4 o = make_ushort4(0, 0, 0, 0);
    if (c + 3 < 15069) {
      o = make_ushort4(f2bf(s[0]), f2bf(s[1]), f2bf(s[2]), f2bf(s[3]));
    } else {
      if (c + 0 < 15069) o.x = f2bf(s[0]);
      if (c + 1 < 15069) o.y = f2bf(s[1]);
      if (c + 2 < 15069) o.z = f2bf(s[2]);
      if (c + 3 < 15069) o.w = f2bf(s[3]);
    }
    ((ushort4*)Wvmh)[i] = o;
  } else {
    const int j = (bid - 23040) * 256 + threadIdx.x;
    if (j < 98304) {
      float4 v = ((const float4*)audio)[j];
      ((ushort4*)audh)[j] = make_ushort4(f2bf(v.x), f2bf(v.y), f2bf(v.z), f2bf(v.w));
    }
  }
}

// ---------------- reduce_pe: vin fp32 partials + style + PE -> x (f32 + bf16) ----------------
__global__ __launch_bounds__(256) void reduce_pe(const float* __restrict__ part,
                                                 const float* __restrict__ one_hot,
                                                 const float* __restrict__ W_obj,
                                                 const float* __restrict__ b_vm,
                                                 float* __restrict__ x,
                                                 ushort_t* __restrict__ xh) {
  const int t = blockIdx.x;
  const float PECOEF = -9.210340371976184f / 512.f;  // -ln(10000)/512
  const int p = t % 25;
  for (int d = threadIdx.x; d < 1024; d += 256) {
    float s = b_vm[d];
    #pragma unroll
    for (int j = 0; j < 8; ++j) s += one_hot[j] * W_obj[d * 8 + j];
    #pragma unroll
    for (int z = 0; z < 16; ++z) s += part[(size_t)z * 524288 + (size_t)t * 1024 + d];
    float arg = (float)p * expf((float)(d >> 1) * PECOEF);
    s += (d & 1) ? cosf(arg) : sinf(arg);
    const size_t idx = (size_t)t * 1024 + d;
    x[idx] = s;
    xh[idx] = f2bf(s);
  }
}

// ---------------- merged qkv post (bf16 partials): combine(qkv) + vT + combine(hid) ----------------
__global__ __launch_bounds__(256) void qkvpost_combhid(
    const ushort_t* __restrict__ partQ, const float* __restrict__ bias,
    ushort_t* __restrict__ qkvh, ushort_t* __restrict__ vth,
    const ushort_t* __restrict__ partH, const float* __restrict__ b_af,
    ushort_t* __restrict__ hidh)
{
  const int bid = blockIdx.x;
  __shared__ float tile[32][33];
  if (bid < 1536) {
    const int i = bid * 256 + threadIdx.x;
    float4 s = ((const float4*)bias)[i % 768];
    #pragma unroll
    for (int z = 0; z < 4; ++z) {
      ushort4 p = ((const ushort4*)(partQ + (size_t)z * 1572864))[i];
      s.x += bf2f(p.x); s.y += bf2f(p.y); s.z += bf2f(p.z); s.w += bf2f(p.w);
    }
    ((ushort4*)qkvh)[i] = make_ushort4(f2bf(s.x), f2bf(s.y), f2bf(s.z), f2bf(s.w));
  } else if (bid < 2048) {
    const int b = bid - 1536;
    const int s0 = (b & 15) * 32, d0 = (b >> 4) * 32;
    const int tx = threadIdx.x & 31, ty = threadIdx.x >> 5;
    for (int r = ty; r < 32; r += 8) {
      float v = bias[2048 + d0 + tx];
      #pragma unroll
      for (int z = 0; z < 4; ++z)
        v += bf2f(partQ[(size_t)z * 1572864 + (size_t)(s0 + r) * 3072 + 2048 + d0 + tx]);
      tile[r][tx] = v;
    }
    __syncthreads();
    for (int r = ty; r < 32; r += 8)
      vth[(size_t)(d0 + r) * 512 + s0 + tx] = f2bf(tile[tx][r]);
  } else {
    const int i = (bid - 2048) * 256 + threadIdx.x;   // < 131072
    float4 s = ((const float4*)b_af)[i % 256];
    #pragma unroll
    for (int z = 0; z < 4; ++z) {
      ushort4 p = ((const ushort4*)(partH + (size_t)z * 524288))[i];
      s.x += bf2f(p.x); s.y += bf2f(p.y); s.z += bf2f(p.z); s.w += bf2f(p.w);
    }
    ((ushort4*)hidh)[i] = make_ushort4(f2bf(s.x), f2bf(s.y), f2bf(s.z), f2bf(s.w));
  }
}

// ---------------- merged: softmax (2048, fp32 scores) + combine(cv) (512, bf16 partials) ----------------
__global__ __launch_bounds__(256) void sm_combcv(
    const float* __restrict__ scores, ushort_t* __restrict__ ah,
    const ushort_t* __restrict__ partCV, const float* __restrict__ bqkv_ca,
    ushort_t* __restrict__ cvh)
{
  const int bid = blockIdx.x;
  __shared__ float red[4];
  if (bid < 2048) {
    const int i = bid & 511, h = bid >> 9;
    const float* r0 = scores + (size_t)(2 * h) * 262144 + (size_t)i * 512;
    const float* r1 = r0 + 262144;
    const size_t rb = ((size_t)h * 512 + i) * 512;
    const int tid = threadIdx.x;
    const int len = i + 1;
    const float sl = exp2f(-2.f * (float)(h + 1));
    const int j0 = tid, j1 = tid + 256;
    float v0 = -INFINITY, v1 = -INFINITY;
    if (j0 < len) v0 = (r0[j0] + r1[j0]) * 0.0625f - sl * (float)((i - j0) / 25);
    if (j1 < len) v1 = (r0[j1] + r1[j1]) * 0.0625f - sl * (float)((i - j1) / 25);
    float m = blockReduceMax256(fmaxf(v0, v1), red);
    float e0 = (j0 < len) ? expf(v0 - m) : 0.f;
    float e1 = (j1 < len) ? expf(v1 - m) : 0.f;
    float s = blockReduceSum256(e0 + e1, red);
    float inv = 1.f / s;
    ah[rb + j0] = f2bf(e0 * inv);
    ah[rb + j1] = f2bf(e1 * inv);
  } else {
    const int i = (bid - 2048) * 256 + threadIdx.x;   // < 131072
    float4 s = ((const float4*)(bqkv_ca + 2048))[i % 256];
    #pragma unroll
    for (int z = 0; z < 8; ++z) {
      ushort4 p = ((const ushort4*)(partCV + (size_t)z * 524288))[i];
      s.x += bf2f(p.x); s.y += bf2f(p.y); s.z += bf2f(p.z); s.w += bf2f(p.w);
    }
    ((ushort4*)cvh)[i] = make_ushort4(f2bf(s.x), f2bf(s.y), f2bf(s.z), f2bf(s.w));
  }
}

// ---------------- host-side launch ----------------
extern "C" void kernel_launch(void* const* d_in, const int* in_sizes, int n_in,
                              void* d_out, int out_size, void* d_ws, size_t ws_size,
                              hipStream_t stream) {
  const float* audio   = (const float*)d_in[0];
  const float* vertice = (const float*)d_in[1];
  const float* tmpl    = (const float*)d_in[2];
  const float* one_hot = (const float*)d_in[3];
  const float* W_af    = (const float*)d_in[4];
  const float* b_af    = (const float*)d_in[5];
  const float* W_vm    = (const float*)d_in[6];
  const float* b_vm    = (const float*)d_in[7];
  const float* W_obj   = (const float*)d_in[8];
  const float* Wqkv_sa = (const float*)d_in[9];
  const float* bqkv_sa = (const float*)d_in[10];
  const float* Wo_sa   = (const float*)d_in[11];
  const float* bo_sa   = (const float*)d_in[12];
  const float* Wqkv_ca = (const float*)d_in[13];
  const float* bqkv_ca = (const float*)d_in[14];
  const float* Wo_ca   = (const float*)d_in[15];
  const float* bo_ca   = (const float*)d_in[16];
  const float* W1      = (const float*)d_in[17];
  const float* b1      = (const float*)d_in[18];
  const float* W2      = (const float*)d_in[19];
  const float* b2      = (const float*)d_in[20];
  const float* g1      = (const float*)d_in[21];
  const float* be1     = (const float*)d_in[22];
  const float* g2      = (const float*)d_in[23];
  const float* be2     = (const float*)d_in[24];
  const float* g3      = (const float*)d_in[25];
  const float* be3     = (const float*)d_in[26];
  const float* W_vr    = (const float*)d_in[27];
  const float* b_vr    = (const float*)d_in[28];
  float* out = (float*)d_out;

  // ---- workspace carve (floats), total ~113 MB ----
  float* base = (float*)d_ws;
  float* apF    = base;                  // 512*15360 us  = 3,932,160 fl
  float* wvmF   = apF + 3932160;         // 1024*15360 us = 7,864,320 fl (Wvm, then Wvr after vin)
  float* part   = wvmF + 7864320;        // 16*524288     = 8,388,608 fl
  float* x      = part + 8388608;        // 524,288
  float* xhF    = x + 524288;            // 262,144 (512*1024 us)
  float* audF   = xhF + 262144;          // 196,608 (512*768 us)
  float* hidF   = audF + 196608;         // 262,144
  float* qkvF   = hidF + 262144;         // 786,432 (512*3072 us)
  float* vtF    = qkvF + 786432;         // 262,144 (1024*512 us)
  float* scores = vtF + 262144;          // 2,097,152 (8 x 512x512 fp32 partials)
  float* attF   = scores + 2097152;      // 524,288 (4*512*512 us)
  float* pvpart = attF + 524288;         // 2,097,152 (16 x 512x256 fp32 partials)
  float* ctxF   = pvpart + 2097152;      // 262,144
  float* cvF    = ctxF + 262144;         // 262,144
  float* h1F    = cvF + 262144;          // 524,288 (512*2048 us)

  // bf16 partial sub-regions inside `part` (disjoint lifetimes, element = ushort):
  ushort_t* partQ  = (ushort_t*)part;                   // 4 x 1,572,864 us (steps 4-5)
  ushort_t* partH  = (ushort_t*)(part + 4194304);       // 4 x   524,288 us (steps 4-5)
  ushort_t* partCV = (ushort_t*)part;                   // 8 x   524,288 us (steps 6-7)
  ushort_t* partCA = (ushort_t*)(part + 4194304);       // 8 x   524,288 us (steps 8-11)
  ushort_t* partSA = (ushort_t*)part;                   // 8 x   524,288 us (steps 10-11)
  ushort_t* partF1 = (ushort_t*)part;                   // 4 x 1,048,576 us (steps 12-13)
  ushort_t* partF2 = (ushort_t*)part;                   // 8 x   524,288 us (steps 14-15)

  ushort_t* Aph  = (ushort_t*)apF;
  ushort_t* Wvmh = (ushort_t*)wvmF;
  ushort_t* Wvrh = (ushort_t*)wvmF;      // alias: Wvm dead after vin GEMM
  ushort_t* xh   = (ushort_t*)xhF;
  ushort_t* audh = (ushort_t*)audF;
  ushort_t* hidh = (ushort_t*)hidF;
  ushort_t* qkvh = (ushort_t*)qkvF;
  ushort_t* vth  = (ushort_t*)vtF;
  ushort_t* atth = (ushort_t*)attF;
  ushort_t* ctxh = (ushort_t*)ctxF;
  ushort_t* cvh  = (ushort_t*)cvF;
  ushort_t* h1h  = (ushort_t*)h1F;

  // 1. prep: vin shift + W_vm cvt + audio cvt (merged)
  prep_all<<<23424, 256, 0, stream>>>(vertice, tmpl, Aph, W_vm, Wvmh, audio, audh);

  // 2. vin = Ap @ Wvm^T (split-K x16, z-fastest, fp32 partials)
  gk<true, 0, false, 1, 0, false><<<dim3(16, 4, 8), 256, 32768, stream>>>(
      Aph, Wvmh, nullptr, nullptr, part,
      1024, KVIN, KVIN, KVIN, 1024, 960, 0, 0, 524288);

  // 3. reduce_pe (vin partials -> x, xh)
  reduce_pe<<<512, 256, 0, stream>>>(part, one_hot, W_obj, b_vm, x, xh);

  // 4. qkv GEMM || hidden GEMM (bf16 partials)
  gk_qkv_hid<<<512, 256, 32768, stream>>>(xh, Wqkv_sa, partQ, audh, W_af, partH);

  // 5. qkv combine + vT transpose + hidden combine (merged)
  qkvpost_combhid<<<2560, 256, 0, stream>>>(partQ, bqkv_sa, qkvh, vth,
                                            partH, b_af, hidh);

  // 6. scores GEMM || CA-V GEMM || W_vr cvt lo-half
  gk_scores_cav<<<1408, 256, 32768, stream>>>(qkvh, scores, hidh,
                                              Wqkv_ca + (size_t)2048 * 1024, partCV,
                                              W_vr, Wvrh);

  // 7. softmax + CA-V combine (merged)
  sm_combcv<<<2560, 256, 0, stream>>>(scores, atth, partCV, bqkv_ca, cvh);

  // 8. PV GEMM || CA-O GEMM || W_vr cvt hi-half
  gk_pv_cao<<<1408, 256, 32768, stream>>>(atth, vth, pvpart, cvh, Wo_ca, partCA,
                                          W_vr, Wvrh);

  // 9. PV combine
  combine_pv<<<512, 256, 0, stream>>>(pvpart, ctxh);

  // 10. SA out-proj (bf16 partials, split-K x8, lower region; CA partials upper survive)
  gk<false, 0, false, 0, 0, true><<<dim3(8, 4, 8), 256, 32768, stream>>>(
      ctxh, Wo_sa, nullptr, nullptr, partSA,
      1024, 1024, 1024, 1024, 1024, 128, 0, 0, 524288);

  // 11. ln1 + ln2 fused (SA 8 partials lower, CA 8 partials upper)
  ln_double<<<512, 256, 0, stream>>>(partSA, bo_sa, partCA, bo_ca,
                                     x, xh, g1, be1, g2, be2);

  // 12. FF1 (bf16 partials, split-K x4)
  gk<false, 0, false, 0, 0, true><<<dim3(16, 4, 4), 256, 32768, stream>>>(
      xh, W1, nullptr, nullptr, partF1,
      2048, 1024, 1024, 1024, 2048, 256, 0, 0, 1048576);
  // 13. FF1 combine + relu
  combine<true><<<1024, 256, 0, stream>>>(partF1, b1, h1h, 4, 1048576, 262144, 512);
  // 14. FF2 (bf16 partials, split-K x8)
  gk<false, 0, false, 0, 0, true><<<dim3(8, 4, 8), 256, 32768, stream>>>(
      h1h, W2, nullptr, nullptr, partF2,
      1024, 2048, 2048, 2048, 1024, 256, 0, 0, 524288);
  // 15. ln3
  ln_parts<<<512, 256, 0, stream>>>(partF2, 8, b2, x, xh, g3, be3);

  // 16. final projection: out = x @ W_vr^T + b_vr + tmpl (XCD n-swizzle, fp32 out)
  gk<true, 2, false, 2, 0, false><<<dim3(480, 1, 1), 256, 32768, stream>>>(
      xh, Wvrh, b_vr, tmpl, out,
      15069, 1024, 1024, 1024, 15069, 0, 0, 0, 0);
}